// Round 10
// baseline (316.091 us; speedup 1.0000x reference)
//
#include <hip/hip_runtime.h>

typedef __bf16 bf16;
typedef _Float16 f16;
typedef __bf16 bf16x8 __attribute__((ext_vector_type(8)));
typedef _Float16 f16x8 __attribute__((ext_vector_type(8)));
typedef float  f32x4  __attribute__((ext_vector_type(4)));

#define B_  8
#define N_  2048
#define F_  256
#define NTOK (B_ * N_)
static constexpr float LOG2E = 1.44269504088896f;

// ---------------------------------------------------------------------------
// dtype detector (bf16-packed vs fp32). Wave-uniform. Proven rounds 3-8.
// ---------------------------------------------------------------------------
__device__ __forceinline__ int detect_bf16(const void* h) {
    const unsigned* hw = (const unsigned*)h;
    unsigned w = hw[threadIdx.x & 63];
    unsigned ex = (w >> 7) & 0xFFu;
    unsigned long long b = __ballot(ex > 100u && ex < 150u);
    return __popcll(b) >= 40;
}

__device__ __forceinline__ float ldf(const void* p, int i, int isb) {
    return isb ? (float)((const bf16*)p)[i] : ((const float*)p)[i];
}

__device__ __forceinline__ bf16x8 cvt8(const float* p) {
    float4 a = *(const float4*)p;
    float4 b = *(const float4*)(p + 4);
    bf16x8 r;
    r[0]=(bf16)a.x; r[1]=(bf16)a.y; r[2]=(bf16)a.z; r[3]=(bf16)a.w;
    r[4]=(bf16)b.x; r[5]=(bf16)b.y; r[6]=(bf16)b.z; r[7]=(bf16)b.w;
    return r;
}

// WhT2 tiled layout: elem index for (b, f, n):
//   tile = b*32 + (n>>6); within tile: row f (64 elems), phys slot
//   ((n>>3)&7) ^ (f&7)  (XOR swizzle baked in), byte elem n&7.
__device__ __forceinline__ size_t wht2_idx(int b, int f, int n) {
    int jc = n >> 6;
    int slot = ((n >> 3) & 7) ^ (f & 7);
    return (((size_t)(b * 32 + jc) * F_ + f) << 6) + (slot << 3) + (n & 7);
}

// ---------------------------------------------------------------------------
// Kernel A (fused s/t): WhT2 = tiled/swizzled Wh; s,t stashed f16 in high
// halves of adjw[token] (t) and adjw[NTOK+token] (s). Mask bits preserved.
// Unchanged from round 8 (passing).
// ---------------------------------------------------------------------------
__global__ __launch_bounds__(256)
void k_wht(const void* __restrict__ hv, const void* __restrict__ Wv,
           const void* __restrict__ Wbv, const void* __restrict__ ai_wv,
           const void* __restrict__ ai_bv, const void* __restrict__ aj_wv,
           const void* __restrict__ aj_bv, bf16* __restrict__ WhT2,
           unsigned* __restrict__ adjw) {
    int isb = detect_bf16(hv);
    int ttile = blockIdx.x;            // 1024 token-tiles of 16
    int fg = threadIdx.x >> 6;         // 4 f-groups of 64
    int lane = threadIdx.x & 63;
    int T0 = ttile * 16;
    int m = lane & 15, quad = lane >> 4;

    f32x4 acc[4];
#pragma unroll
    for (int ft = 0; ft < 4; ++ft) acc[ft] = (f32x4){0.f, 0.f, 0.f, 0.f};

    if (isb) {
        const bf16* hp = (const bf16*)hv + (size_t)(T0 + m) * F_ + quad * 8;
        const bf16* wp = (const bf16*)Wv + (size_t)(fg * 64 + m) * F_ + quad * 8;
#pragma unroll
        for (int kk = 0; kk < F_; kk += 32) {
            bf16x8 hf = *(const bf16x8*)(hp + kk);
#pragma unroll
            for (int ft = 0; ft < 4; ++ft) {
                bf16x8 wf = *(const bf16x8*)(wp + (size_t)ft * 16 * F_ + kk);
                acc[ft] = __builtin_amdgcn_mfma_f32_16x16x32_bf16(wf, hf, acc[ft], 0, 0, 0);
            }
        }
    } else {
        const float* hp = (const float*)hv + (size_t)(T0 + m) * F_ + quad * 8;
        const float* wp = (const float*)Wv + (size_t)(fg * 64 + m) * F_ + quad * 8;
#pragma unroll
        for (int kk = 0; kk < F_; kk += 32) {
            bf16x8 hf = cvt8(hp + kk);
#pragma unroll
            for (int ft = 0; ft < 4; ++ft) {
                bf16x8 wf = cvt8(wp + (size_t)ft * 16 * F_ + kk);
                acc[ft] = __builtin_amdgcn_mfma_f32_16x16x32_bf16(wf, hf, acc[ft], 0, 0, 0);
            }
        }
    }
    int token = T0 + m;
    int b = token >> 11, n = token & (N_ - 1);
    float s_p = 0.f, t_p = 0.f;
#pragma unroll
    for (int ft = 0; ft < 4; ++ft)
#pragma unroll
        for (int r = 0; r < 4; ++r) {
            int f = fg * 64 + ft * 16 + quad * 4 + r;
            float v = acc[ft][r] + ldf(Wbv, f, isb);
            bf16 vb = (bf16)v;
            WhT2[wht2_idx(b, f, n)] = vb;
            float vr = (float)vb;                    // rounded, matches WhT2
            s_p += vr * ldf(ai_wv, f, isb);
            t_p += vr * ldf(aj_wv, f, isb);
        }
    s_p += __shfl_down(s_p, 32, 64); s_p += __shfl_down(s_p, 16, 64);
    t_p += __shfl_down(t_p, 32, 64); t_p += __shfl_down(t_p, 16, 64);
    __shared__ float sred[4][16], tred[4][16];
    if (lane < 16) { sred[fg][lane] = s_p; tred[fg][lane] = t_p; }
    __syncthreads();
    if (threadIdx.x < 16) {
        int tid = threadIdx.x;
        int tok = T0 + tid;
        float ss = (sred[0][tid] + sred[1][tid] + sred[2][tid] + sred[3][tid]
                    + ldf(ai_bv, 0, isb)) * LOG2E;
        float tt = (tred[0][tid] + tred[1][tid] + tred[2][tid] + tred[3][tid]
                    + ldf(aj_bv, 0, isb)) * LOG2E;
        f16 th = (f16)tt, sh = (f16)ss;
        unsigned short tu, su;
        __builtin_memcpy(&tu, &th, 2);
        __builtin_memcpy(&su, &sh, 2);
        unsigned w0 = adjw[tok];
        adjw[tok] = (w0 & 0xFFFFu) | ((unsigned)tu << 16);
        unsigned w1 = adjw[NTOK + tok];
        adjw[NTOK + tok] = (w1 & 0xFFFFu) | ((unsigned)su << 16);
    }
}

// ---------------------------------------------------------------------------
// Kernel C: fused masked-softmax attention + PV + ELU. R=32 rows/block,
// 512 blocks x 256 thr; 4 waves = (j-half jh) x (f-half fh). Prologue packs
// ALL masks + t2 slab; main loop: barrier every 4 chunks (bounded pipeline
// window), B-frags global->VGPR from tiled WhT2 (L2), each B-frag feeds both
// m-tiles, l via ones-MFMA. x clamped [-120,60]: arithmetic cannot NaN/Inf.
// ---------------------------------------------------------------------------
__global__ __launch_bounds__(256)
void k_attn(const unsigned* __restrict__ adjw, const bf16* __restrict__ WhT2,
            const void* __restrict__ hv, void* __restrict__ outv) {
    int isb = detect_bf16(hv);
    int bid = blockIdx.x;
    int b = bid >> 6, itile = bid & 63, i0 = itile * 32;
    int tid = threadIdx.x;
    int w = tid >> 6, lane = tid & 63, m = lane & 15, q = lane >> 4;
    int jh = w & 1, fh = w >> 1;

    __shared__ __align__(16) char smem[33280];
    unsigned long long* pack64 = (unsigned long long*)smem;  // [32][33] = 8448 B
    f16*   tLDS = (f16*)(smem + 8448);                       // [2048] = 4096 B
    float* red  = (float*)smem;                              // epi overlay [32][260]
    __shared__ float lLDS[2][32];

    // ---- prologue: t2 slab ----
#pragma unroll
    for (int k = 0; k < 8; ++k) {
        int idx = k * 256 + tid;
        unsigned wv = adjw[b * N_ + idx];
        unsigned short us = (unsigned short)(wv >> 16);
        f16 tv; __builtin_memcpy(&tv, &us, 2);
        tLDS[idx] = tv;
    }
    // s2 for this lane's two rows (mt=0,1)
    float s2i0, s2i1;
    {
        unsigned sw0 = adjw[NTOK + b * N_ + i0 + m];
        unsigned sw1 = adjw[NTOK + b * N_ + i0 + 16 + m];
        unsigned short u0 = (unsigned short)(sw0 >> 16);
        unsigned short u1 = (unsigned short)(sw1 >> 16);
        f16 h0, h1;
        __builtin_memcpy(&h0, &u0, 2); __builtin_memcpy(&h1, &u1, 2);
        s2i0 = (float)h0; s2i1 = (float)h1;
    }
    // ---- prologue: pack all 32 rows x 2048 j -> 1024 u64, 4 per thread ----
#pragma unroll
    for (int k = 0; k < 4; ++k) {
        int id = tid * 4 + k;                  // [0,1024)
        int prow = id >> 5, pc = id & 31;
        const unsigned* src = adjw + ((size_t)(b * N_ + i0 + prow)) * N_ + pc * 64;
        unsigned long long bits = 0;
#pragma unroll
        for (int w8 = 0; w8 < 16; ++w8) {
            uint4 a = *(const uint4*)(src + w8 * 4);
            bits |= (unsigned long long)((a.x & 1u) | ((a.y & 1u) << 1) |
                                         ((a.z & 1u) << 2) | ((a.w & 1u) << 3))
                    << (w8 * 4);
        }
        pack64[prow * 33 + pc] = bits;
    }
    __syncthreads();

    bf16x8 ones;
#pragma unroll
    for (int k = 0; k < 8; ++k) ones[k] = (bf16)1.0f;

    f32x4 acc0[8], acc1[8];
#pragma unroll
    for (int ft = 0; ft < 8; ++ft) {
        acc0[ft] = (f32x4){0.f, 0.f, 0.f, 0.f};
        acc1[ft] = (f32x4){0.f, 0.f, 0.f, 0.f};
    }
    f32x4 acc_l0 = {0.f, 0.f, 0.f, 0.f}, acc_l1 = {0.f, 0.f, 0.f, 0.f};

    int psl = (jh * 4 + q) ^ (m & 7);          // phys 16B slot (swizzle baked)
    const size_t tilestep = (size_t)F_ * 64;   // 16384 elems
    const bf16* btile = WhT2 + (size_t)(b * 32) * tilestep +
                        (size_t)(fh * 128) * 64 + m * 64 + psl * 8;
    int byi = jh * 4 + q;                      // byte index into u64

    for (int c = 0; c < 32; ++c) {
        unsigned long long pb0 = pack64[m * 33 + c];
        unsigned long long pb1 = pack64[(16 + m) * 33 + c];
        unsigned bits0 = (unsigned)(pb0 >> (byi * 8)) & 0xFFu;
        unsigned bits1 = (unsigned)(pb1 >> (byi * 8)) & 0xFFu;
        f16x8 tv = *(const f16x8*)(tLDS + c * 64 + jh * 32 + q * 8);

        bf16x8 af0, af1;
#pragma unroll
        for (int qq = 0; qq < 8; ++qq) {
            float tvf = (float)tv[qq];
            float x0 = s2i0 + tvf, x1 = s2i1 + tvf;
            x0 = fmaxf(x0, 0.2f * x0);               // LeakyReLU (log2-scaled)
            x1 = fmaxf(x1, 0.2f * x1);
            x0 = fminf(fmaxf(x0, -120.f), 60.f);     // NaN/Inf-proof clamp
            x1 = fminf(fmaxf(x1, -120.f), 60.f);
            float p0 = ((bits0 >> qq) & 1u) ? __builtin_amdgcn_exp2f(x0) : 0.f;
            float p1 = ((bits1 >> qq) & 1u) ? __builtin_amdgcn_exp2f(x1) : 0.f;
            af0[qq] = (bf16)p0;
            af1[qq] = (bf16)p1;
        }
        if (fh == 0) {
            acc_l0 = __builtin_amdgcn_mfma_f32_16x16x32_bf16(af0, ones, acc_l0, 0, 0, 0);
            acc_l1 = __builtin_amdgcn_mfma_f32_16x16x32_bf16(af1, ones, acc_l1, 0, 0, 0);
        }
        const bf16* bp = btile + (size_t)c * tilestep;
#pragma unroll
        for (int ft = 0; ft < 8; ++ft) {
            bf16x8 bfr = *(const bf16x8*)(bp + ft * 1024);
            acc0[ft] = __builtin_amdgcn_mfma_f32_16x16x32_bf16(af0, bfr, acc0[ft], 0, 0, 0);
            acc1[ft] = __builtin_amdgcn_mfma_f32_16x16x32_bf16(af1, bfr, acc1[ft], 0, 0, 0);
        }
        if ((c & 3) == 3) __syncthreads();     // bound the pipeline window
    }

    // ---- epilogue ----
    __syncthreads();                 // pack64/tLDS dead; red overlay live
    if (fh == 0 && m == 0) {
#pragma unroll
        for (int r = 0; r < 4; ++r) {
            lLDS[jh][q * 4 + r]      = acc_l0[r];
            lLDS[jh][16 + q * 4 + r] = acc_l1[r];
        }
    }
    if (jh == 1) {
#pragma unroll
        for (int r = 0; r < 4; ++r) {
            int r0 = q * 4 + r, r1 = 16 + q * 4 + r;
#pragma unroll
            for (int ft = 0; ft < 8; ++ft) {
                red[r0 * 260 + fh * 128 + ft * 16 + m] = acc0[ft][r];
                red[r1 * 260 + fh * 128 + ft * 16 + m] = acc1[ft][r];
            }
        }
    }
    __syncthreads();
    if (jh == 0) {
#pragma unroll
        for (int mt = 0; mt < 2; ++mt) {
#pragma unroll
            for (int r = 0; r < 4; ++r) {
                int row = mt * 16 + q * 4 + r;
                float lf = lLDS[0][row] + lLDS[1][row];
                float rl = (lf > 0.f) ? (1.f / lf) : 0.f;
                size_t ob = ((size_t)b * N_ + i0 + row) * F_;
#pragma unroll
                for (int ft = 0; ft < 8; ++ft) {
                    int f = fh * 128 + ft * 16 + m;
                    float v = (mt ? acc1[ft][r] : acc0[ft][r]) + red[row * 260 + f];
                    v *= rl;
                    v = (v > 0.f) ? v : (__builtin_amdgcn_exp2f(v * LOG2E) - 1.f);
                    if (isb) ((bf16*)outv)[ob + f] = (bf16)v;
                    else     ((float*)outv)[ob + f] = v;
                }
            }
        }
    }
}

// ---------------------------------------------------------------------------
extern "C" void kernel_launch(void* const* d_in, const int* in_sizes, int n_in,
                              void* d_out, int out_size, void* d_ws, size_t ws_size,
                              hipStream_t stream) {
    (void)in_sizes; (void)n_in; (void)out_size; (void)ws_size;
    const void* h    = d_in[0];
    unsigned*   adjw = (unsigned*)d_in[1];   // int32 adj; high 16 bits reused
    const void* W_w  = d_in[2];
    const void* W_b  = d_in[3];
    const void* ai_w = d_in[4];
    const void* ai_b = d_in[5];
    const void* aj_w = d_in[6];
    const void* aj_b = d_in[7];

    bf16* WhT2 = (bf16*)d_ws;   // exactly 8 MiB — the ONLY d_ws use

    k_wht <<<dim3(1024), dim3(256), 0, stream>>>(h, W_w, W_b, ai_w, ai_b,
                                                 aj_w, aj_b, WhT2, adjw);
    k_attn<<<dim3(512),  dim3(256), 0, stream>>>(adjw, WhT2, h, d_out);
}

// Round 11
// 301.127 us; speedup vs baseline: 1.0497x; 1.0497x over previous
//
#include <hip/hip_runtime.h>

typedef __bf16 bf16;
typedef _Float16 f16;
typedef __bf16 bf16x8 __attribute__((ext_vector_type(8)));
typedef _Float16 f16x8 __attribute__((ext_vector_type(8)));
typedef float  f32x4  __attribute__((ext_vector_type(4)));

#define B_  8
#define N_  2048
#define F_  256
#define NTOK (B_ * N_)
static constexpr float LOG2E = 1.44269504088896f;

// ---------------------------------------------------------------------------
// dtype detector (bf16-packed vs fp32). Wave-uniform. Proven rounds 3-10.
// ---------------------------------------------------------------------------
__device__ __forceinline__ int detect_bf16(const void* h) {
    const unsigned* hw = (const unsigned*)h;
    unsigned w = hw[threadIdx.x & 63];
    unsigned ex = (w >> 7) & 0xFFu;
    unsigned long long b = __ballot(ex > 100u && ex < 150u);
    return __popcll(b) >= 40;
}

__device__ __forceinline__ float ldf(const void* p, int i, int isb) {
    return isb ? (float)((const bf16*)p)[i] : ((const float*)p)[i];
}

__device__ __forceinline__ bf16x8 cvt8(const float* p) {
    float4 a = *(const float4*)p;
    float4 b = *(const float4*)(p + 4);
    bf16x8 r;
    r[0]=(bf16)a.x; r[1]=(bf16)a.y; r[2]=(bf16)a.z; r[3]=(bf16)a.w;
    r[4]=(bf16)b.x; r[5]=(bf16)b.y; r[6]=(bf16)b.z; r[7]=(bf16)b.w;
    return r;
}

// WhT2 tiled layout: elem index for (b, f, n):
//   tile = b*32 + (n>>6); within tile: row f (64 elems), phys slot
//   ((n>>3)&7) ^ (f&7)  (XOR swizzle baked in), byte elem n&7.
__device__ __forceinline__ size_t wht2_idx(int b, int f, int n) {
    int jc = n >> 6;
    int slot = ((n >> 3) & 7) ^ (f & 7);
    return (((size_t)(b * 32 + jc) * F_ + f) << 6) + (slot << 3) + (n & 7);
}

// ---------------------------------------------------------------------------
// Kernel A (fused s/t): WhT2 = tiled/swizzled Wh; s,t stashed f16 in high
// halves of adjw[token] (t) and adjw[NTOK+token] (s). Unchanged (rounds 8-10).
// ---------------------------------------------------------------------------
__global__ __launch_bounds__(256)
void k_wht(const void* __restrict__ hv, const void* __restrict__ Wv,
           const void* __restrict__ Wbv, const void* __restrict__ ai_wv,
           const void* __restrict__ ai_bv, const void* __restrict__ aj_wv,
           const void* __restrict__ aj_bv, bf16* __restrict__ WhT2,
           unsigned* __restrict__ adjw) {
    int isb = detect_bf16(hv);
    int ttile = blockIdx.x;            // 1024 token-tiles of 16
    int fg = threadIdx.x >> 6;         // 4 f-groups of 64
    int lane = threadIdx.x & 63;
    int T0 = ttile * 16;
    int m = lane & 15, quad = lane >> 4;

    f32x4 acc[4];
#pragma unroll
    for (int ft = 0; ft < 4; ++ft) acc[ft] = (f32x4){0.f, 0.f, 0.f, 0.f};

    if (isb) {
        const bf16* hp = (const bf16*)hv + (size_t)(T0 + m) * F_ + quad * 8;
        const bf16* wp = (const bf16*)Wv + (size_t)(fg * 64 + m) * F_ + quad * 8;
#pragma unroll
        for (int kk = 0; kk < F_; kk += 32) {
            bf16x8 hf = *(const bf16x8*)(hp + kk);
#pragma unroll
            for (int ft = 0; ft < 4; ++ft) {
                bf16x8 wf = *(const bf16x8*)(wp + (size_t)ft * 16 * F_ + kk);
                acc[ft] = __builtin_amdgcn_mfma_f32_16x16x32_bf16(wf, hf, acc[ft], 0, 0, 0);
            }
        }
    } else {
        const float* hp = (const float*)hv + (size_t)(T0 + m) * F_ + quad * 8;
        const float* wp = (const float*)Wv + (size_t)(fg * 64 + m) * F_ + quad * 8;
#pragma unroll
        for (int kk = 0; kk < F_; kk += 32) {
            bf16x8 hf = cvt8(hp + kk);
#pragma unroll
            for (int ft = 0; ft < 4; ++ft) {
                bf16x8 wf = cvt8(wp + (size_t)ft * 16 * F_ + kk);
                acc[ft] = __builtin_amdgcn_mfma_f32_16x16x32_bf16(wf, hf, acc[ft], 0, 0, 0);
            }
        }
    }
    int token = T0 + m;
    int b = token >> 11, n = token & (N_ - 1);
    float s_p = 0.f, t_p = 0.f;
#pragma unroll
    for (int ft = 0; ft < 4; ++ft)
#pragma unroll
        for (int r = 0; r < 4; ++r) {
            int f = fg * 64 + ft * 16 + quad * 4 + r;
            float v = acc[ft][r] + ldf(Wbv, f, isb);
            bf16 vb = (bf16)v;
            WhT2[wht2_idx(b, f, n)] = vb;
            float vr = (float)vb;                    // rounded, matches WhT2
            s_p += vr * ldf(ai_wv, f, isb);
            t_p += vr * ldf(aj_wv, f, isb);
        }
    s_p += __shfl_down(s_p, 32, 64); s_p += __shfl_down(s_p, 16, 64);
    t_p += __shfl_down(t_p, 32, 64); t_p += __shfl_down(t_p, 16, 64);
    __shared__ float sred[4][16], tred[4][16];
    if (lane < 16) { sred[fg][lane] = s_p; tred[fg][lane] = t_p; }
    __syncthreads();
    if (threadIdx.x < 16) {
        int tid = threadIdx.x;
        int tok = T0 + tid;
        float ss = (sred[0][tid] + sred[1][tid] + sred[2][tid] + sred[3][tid]
                    + ldf(ai_bv, 0, isb)) * LOG2E;
        float tt = (tred[0][tid] + tred[1][tid] + tred[2][tid] + tred[3][tid]
                    + ldf(aj_bv, 0, isb)) * LOG2E;
        f16 th = (f16)tt, sh = (f16)ss;
        unsigned short tu, su;
        __builtin_memcpy(&tu, &th, 2);
        __builtin_memcpy(&su, &sh, 2);
        unsigned w0 = adjw[tok];
        adjw[tok] = (w0 & 0xFFFFu) | ((unsigned)tu << 16);
        unsigned w1 = adjw[NTOK + tok];
        adjw[NTOK + tok] = (w1 & 0xFFFFu) | ((unsigned)su << 16);
    }
}

// stage one 32 KB chunk tile: pure contiguous DMA (swizzle pre-baked).
// 4 waves x 8 instrs x (64 lanes x 16 B contiguous). Verified round 8.
__device__ __forceinline__ void stageB(const bf16* tile, char* dst,
                                       int w, int lane) {
#pragma unroll
    for (int r = 0; r < 8; ++r) {
        int off = (w * 8 + r) * 1024;               // bytes, wave-uniform
        const bf16* g = tile + off / 2 + lane * 8;
        __builtin_amdgcn_global_load_lds(
            (const __attribute__((address_space(1))) unsigned*)g,
            (__attribute__((address_space(3))) unsigned*)(dst + off),
            16, 0, 0);
    }
}

// ---------------------------------------------------------------------------
// Kernel C: fused masked-softmax attention + PV + ELU. R=32 rows/block,
// 512 blocks x 256 thr; waves = (jh, fh). Masks packed ONCE in prologue
// (round 10 mapping); B chunks DMA'd to dbuf LDS (round 8 mechanism); each
// B-frag feeds both m-tiles (8 ds_read_b128/chunk/wave, no duplication);
// l via ones-MFMA; clamp keeps arithmetic NaN/Inf-proof.
// ---------------------------------------------------------------------------
__global__ __launch_bounds__(256)
void k_attn(const unsigned* __restrict__ adjw, const bf16* __restrict__ WhT2,
            const void* __restrict__ hv, void* __restrict__ outv) {
    int isb = detect_bf16(hv);
    int bid = blockIdx.x;
    int b = bid >> 6, itile = bid & 63, i0 = itile * 32;
    int tid = threadIdx.x;
    int w = tid >> 6, lane = tid & 63, m = lane & 15, q = lane >> 4;
    int jh = w & 1, fh = w >> 1;

    __shared__ __align__(16) char smem[78080];
    char* Bbuf0 = smem;                                       // 32 KB
    char* Bbuf1 = smem + 32768;                               // 32 KB
    unsigned long long* pack64 = (unsigned long long*)(smem + 65536); // [32][33]
    f16*   tLDS = (f16*)(smem + 65536 + 8448);                // [2048]
    float* red  = (float*)smem;              // epilogue overlay [32][260] (Bbufs dead)
    __shared__ float lLDS[2][32];

    // ---- prologue: t2 slab ----
#pragma unroll
    for (int k = 0; k < 8; ++k) {
        int idx = k * 256 + tid;
        unsigned wv = adjw[b * N_ + idx];
        unsigned short us = (unsigned short)(wv >> 16);
        f16 tv; __builtin_memcpy(&tv, &us, 2);
        tLDS[idx] = tv;
    }
    // s2 for this lane's two rows
    float s2i0, s2i1;
    {
        unsigned sw0 = adjw[NTOK + b * N_ + i0 + m];
        unsigned sw1 = adjw[NTOK + b * N_ + i0 + 16 + m];
        unsigned short u0 = (unsigned short)(sw0 >> 16);
        unsigned short u1 = (unsigned short)(sw1 >> 16);
        f16 h0, h1;
        __builtin_memcpy(&h0, &u0, 2); __builtin_memcpy(&h1, &u1, 2);
        s2i0 = (float)h0; s2i1 = (float)h1;
    }
    // ---- prologue: pack all 32 rows x 2048 j -> 1024 u64 (round 10 map) ----
#pragma unroll
    for (int k = 0; k < 4; ++k) {
        int id = tid * 4 + k;                  // [0,1024)
        int prow = id >> 5, pc = id & 31;
        const unsigned* src = adjw + ((size_t)(b * N_ + i0 + prow)) * N_ + pc * 64;
        unsigned long long bits = 0;
#pragma unroll
        for (int w8 = 0; w8 < 16; ++w8) {
            uint4 a = *(const uint4*)(src + w8 * 4);
            bits |= (unsigned long long)((a.x & 1u) | ((a.y & 1u) << 1) |
                                         ((a.z & 1u) << 2) | ((a.w & 1u) << 3))
                    << (w8 * 4);
        }
        pack64[prow * 33 + pc] = bits;
    }
    const size_t tilestep = (size_t)F_ * 64;   // 16384 elems per chunk tile
    const bf16* btiles = WhT2 + (size_t)(b * 32) * tilestep;
    stageB(btiles, Bbuf0, w, lane);
    __syncthreads();

    bf16x8 ones;
#pragma unroll
    for (int k = 0; k < 8; ++k) ones[k] = (bf16)1.0f;

    f32x4 acc0[8], acc1[8];
#pragma unroll
    for (int ft = 0; ft < 8; ++ft) {
        acc0[ft] = (f32x4){0.f, 0.f, 0.f, 0.f};
        acc1[ft] = (f32x4){0.f, 0.f, 0.f, 0.f};
    }
    f32x4 acc_l0 = {0.f, 0.f, 0.f, 0.f}, acc_l1 = {0.f, 0.f, 0.f, 0.f};

    int psl = (jh * 4 + q) ^ (m & 7);          // phys 16B slot (swizzle baked)
    int byi = jh * 4 + q;                      // byte index into u64

    for (int c = 0; c < 32; ++c) {
        char* Bcur = (c & 1) ? Bbuf1 : Bbuf0;
        if (c < 31)
            stageB(btiles + (size_t)(c + 1) * tilestep,
                   (c & 1) ? Bbuf0 : Bbuf1, w, lane);

        unsigned long long pb0 = pack64[m * 33 + c];
        unsigned long long pb1 = pack64[(16 + m) * 33 + c];
        unsigned bits0 = (unsigned)(pb0 >> (byi * 8)) & 0xFFu;
        unsigned bits1 = (unsigned)(pb1 >> (byi * 8)) & 0xFFu;
        f16x8 tv = *(const f16x8*)(tLDS + c * 64 + jh * 32 + q * 8);

        bf16x8 af0, af1;
#pragma unroll
        for (int qq = 0; qq < 8; ++qq) {
            float tvf = (float)tv[qq];
            float x0 = s2i0 + tvf, x1 = s2i1 + tvf;
            x0 = fmaxf(x0, 0.2f * x0);               // LeakyReLU (log2-scaled)
            x1 = fmaxf(x1, 0.2f * x1);
            x0 = fminf(fmaxf(x0, -120.f), 60.f);     // NaN/Inf-proof clamp
            x1 = fminf(fmaxf(x1, -120.f), 60.f);
            float p0 = ((bits0 >> qq) & 1u) ? __builtin_amdgcn_exp2f(x0) : 0.f;
            float p1 = ((bits1 >> qq) & 1u) ? __builtin_amdgcn_exp2f(x1) : 0.f;
            af0[qq] = (bf16)p0;
            af1[qq] = (bf16)p1;
        }
        if (fh == 0) {
            acc_l0 = __builtin_amdgcn_mfma_f32_16x16x32_bf16(af0, ones, acc_l0, 0, 0, 0);
            acc_l1 = __builtin_amdgcn_mfma_f32_16x16x32_bf16(af1, ones, acc_l1, 0, 0, 0);
        }
#pragma unroll
        for (int ft = 0; ft < 8; ++ft) {
            int fr = fh * 128 + ft * 16 + m;
            bf16x8 bfr = *(const bf16x8*)(Bcur + fr * 128 + psl * 16);
            acc0[ft] = __builtin_amdgcn_mfma_f32_16x16x32_bf16(af0, bfr, acc0[ft], 0, 0, 0);
            acc1[ft] = __builtin_amdgcn_mfma_f32_16x16x32_bf16(af1, bfr, acc1[ft], 0, 0, 0);
        }
        __syncthreads();
    }

    // ---- epilogue (round 10, verified) ----
    if (fh == 0 && m == 0) {
#pragma unroll
        for (int r = 0; r < 4; ++r) {
            lLDS[jh][q * 4 + r]      = acc_l0[r];
            lLDS[jh][16 + q * 4 + r] = acc_l1[r];
        }
    }
    if (jh == 1) {
#pragma unroll
        for (int r = 0; r < 4; ++r) {
            int r0 = q * 4 + r, r1 = 16 + q * 4 + r;
#pragma unroll
            for (int ft = 0; ft < 8; ++ft) {
                red[r0 * 260 + fh * 128 + ft * 16 + m] = acc0[ft][r];
                red[r1 * 260 + fh * 128 + ft * 16 + m] = acc1[ft][r];
            }
        }
    }
    __syncthreads();
    if (jh == 0) {
#pragma unroll
        for (int mt = 0; mt < 2; ++mt) {
#pragma unroll
            for (int r = 0; r < 4; ++r) {
                int row = mt * 16 + q * 4 + r;
                float lf = lLDS[0][row] + lLDS[1][row];
                float rl = (lf > 0.f) ? (1.f / lf) : 0.f;
                size_t ob = ((size_t)b * N_ + i0 + row) * F_;
#pragma unroll
                for (int ft = 0; ft < 8; ++ft) {
                    int f = fh * 128 + ft * 16 + m;
                    float v = (mt ? acc1[ft][r] : acc0[ft][r]) + red[row * 260 + f];
                    v *= rl;
                    v = (v > 0.f) ? v : (__builtin_amdgcn_exp2f(v * LOG2E) - 1.f);
                    if (isb) ((bf16*)outv)[ob + f] = (bf16)v;
                    else     ((float*)outv)[ob + f] = v;
                }
            }
        }
    }
}

// ---------------------------------------------------------------------------
extern "C" void kernel_launch(void* const* d_in, const int* in_sizes, int n_in,
                              void* d_out, int out_size, void* d_ws, size_t ws_size,
                              hipStream_t stream) {
    (void)in_sizes; (void)n_in; (void)out_size; (void)ws_size;
    const void* h    = d_in[0];
    unsigned*   adjw = (unsigned*)d_in[1];   // int32 adj; high 16 bits reused
    const void* W_w  = d_in[2];
    const void* W_b  = d_in[3];
    const void* ai_w = d_in[4];
    const void* ai_b = d_in[5];
    const void* aj_w = d_in[6];
    const void* aj_b = d_in[7];

    bf16* WhT2 = (bf16*)d_ws;   // exactly 8 MiB — the ONLY d_ws use

    k_wht <<<dim3(1024), dim3(256), 0, stream>>>(h, W_w, W_b, ai_w, ai_b,
                                                 aj_w, aj_b, WhT2, adjw);
    k_attn<<<dim3(512),  dim3(256), 0, stream>>>(adjw, WhT2, h, d_out);
}

// Round 12
// 297.105 us; speedup vs baseline: 1.0639x; 1.0135x over previous
//
#include <hip/hip_runtime.h>

typedef __bf16 bf16;
typedef _Float16 f16;
typedef __bf16 bf16x8 __attribute__((ext_vector_type(8)));
typedef _Float16 f16x8 __attribute__((ext_vector_type(8)));
typedef float  f32x4  __attribute__((ext_vector_type(4)));

#define B_  8
#define N_  2048
#define F_  256
#define NTOK (B_ * N_)
static constexpr float LOG2E = 1.44269504088896f;

// ---------------------------------------------------------------------------
// dtype detector (bf16-packed vs fp32). Wave-uniform. Proven rounds 3-11.
// ---------------------------------------------------------------------------
__device__ __forceinline__ int detect_bf16(const void* h) {
    const unsigned* hw = (const unsigned*)h;
    unsigned w = hw[threadIdx.x & 63];
    unsigned ex = (w >> 7) & 0xFFu;
    unsigned long long b = __ballot(ex > 100u && ex < 150u);
    return __popcll(b) >= 40;
}

__device__ __forceinline__ float ldf(const void* p, int i, int isb) {
    return isb ? (float)((const bf16*)p)[i] : ((const float*)p)[i];
}

__device__ __forceinline__ bf16x8 cvt8(const float* p) {
    float4 a = *(const float4*)p;
    float4 b = *(const float4*)(p + 4);
    bf16x8 r;
    r[0]=(bf16)a.x; r[1]=(bf16)a.y; r[2]=(bf16)a.z; r[3]=(bf16)a.w;
    r[4]=(bf16)b.x; r[5]=(bf16)b.y; r[6]=(bf16)b.z; r[7]=(bf16)b.w;
    return r;
}

// WhT2 tiled layout (rounds 8-11, verified): elem index for (b, f, n):
//   tile = b*32 + (n>>6); within tile: row f (64 elems), phys slot
//   ((n>>3)&7) ^ (f&7)  (XOR swizzle baked in), byte elem n&7.
__device__ __forceinline__ size_t wht2_idx(int b, int f, int n) {
    int jc = n >> 6;
    int slot = ((n >> 3) & 7) ^ (f & 7);
    return (((size_t)(b * 32 + jc) * F_ + f) << 6) + (slot << 3) + (n & 7);
}

// ---------------------------------------------------------------------------
// Kernel A: WhT2 = tiled/swizzled Wh; s2/t2 (log2e-scaled) to f32 ws arrays.
// ---------------------------------------------------------------------------
__global__ __launch_bounds__(256)
void k_wht(const void* __restrict__ hv, const void* __restrict__ Wv,
           const void* __restrict__ Wbv, const void* __restrict__ ai_wv,
           const void* __restrict__ ai_bv, const void* __restrict__ aj_wv,
           const void* __restrict__ aj_bv, bf16* __restrict__ WhT2,
           float* __restrict__ s2ws, float* __restrict__ t2ws) {
    int isb = detect_bf16(hv);
    int ttile = blockIdx.x;            // 1024 token-tiles of 16
    int fg = threadIdx.x >> 6;         // 4 f-groups of 64
    int lane = threadIdx.x & 63;
    int T0 = ttile * 16;
    int m = lane & 15, quad = lane >> 4;

    f32x4 acc[4];
#pragma unroll
    for (int ft = 0; ft < 4; ++ft) acc[ft] = (f32x4){0.f, 0.f, 0.f, 0.f};

    if (isb) {
        const bf16* hp = (const bf16*)hv + (size_t)(T0 + m) * F_ + quad * 8;
        const bf16* wp = (const bf16*)Wv + (size_t)(fg * 64 + m) * F_ + quad * 8;
#pragma unroll
        for (int kk = 0; kk < F_; kk += 32) {
            bf16x8 hf = *(const bf16x8*)(hp + kk);
#pragma unroll
            for (int ft = 0; ft < 4; ++ft) {
                bf16x8 wf = *(const bf16x8*)(wp + (size_t)ft * 16 * F_ + kk);
                acc[ft] = __builtin_amdgcn_mfma_f32_16x16x32_bf16(wf, hf, acc[ft], 0, 0, 0);
            }
        }
    } else {
        const float* hp = (const float*)hv + (size_t)(T0 + m) * F_ + quad * 8;
        const float* wp = (const float*)Wv + (size_t)(fg * 64 + m) * F_ + quad * 8;
#pragma unroll
        for (int kk = 0; kk < F_; kk += 32) {
            bf16x8 hf = cvt8(hp + kk);
#pragma unroll
            for (int ft = 0; ft < 4; ++ft) {
                bf16x8 wf = cvt8(wp + (size_t)ft * 16 * F_ + kk);
                acc[ft] = __builtin_amdgcn_mfma_f32_16x16x32_bf16(wf, hf, acc[ft], 0, 0, 0);
            }
        }
    }
    int token = T0 + m;
    int b = token >> 11, n = token & (N_ - 1);
    float s_p = 0.f, t_p = 0.f;
#pragma unroll
    for (int ft = 0; ft < 4; ++ft)
#pragma unroll
        for (int r = 0; r < 4; ++r) {
            int f = fg * 64 + ft * 16 + quad * 4 + r;
            float v = acc[ft][r] + ldf(Wbv, f, isb);
            bf16 vb = (bf16)v;
            WhT2[wht2_idx(b, f, n)] = vb;
            float vr = (float)vb;                    // rounded, matches WhT2
            s_p += vr * ldf(ai_wv, f, isb);
            t_p += vr * ldf(aj_wv, f, isb);
        }
    s_p += __shfl_down(s_p, 32, 64); s_p += __shfl_down(s_p, 16, 64);
    t_p += __shfl_down(t_p, 32, 64); t_p += __shfl_down(t_p, 16, 64);
    __shared__ float sred[4][16], tred[4][16];
    if (lane < 16) { sred[fg][lane] = s_p; tred[fg][lane] = t_p; }
    __syncthreads();
    if (threadIdx.x < 16) {
        int tid = threadIdx.x;
        int tok = T0 + tid;
        s2ws[tok] = (sred[0][tid] + sred[1][tid] + sred[2][tid] + sred[3][tid]
                     + ldf(ai_bv, 0, isb)) * LOG2E;
        t2ws[tok] = (tred[0][tid] + tred[1][tid] + tred[2][tid] + tred[3][tid]
                     + ldf(aj_bv, 0, isb)) * LOG2E;
    }
}

// ---------------------------------------------------------------------------
// Kernel P: global mask bit-pack. bitmap[grow*32+pc] holds bits for
// adj[grow][pc*64 .. pc*64+63]; bit (w8*4+e) = adj word (pc*64+w8*4+e) & 1.
// Mapping byte-identical to rounds 10/11's verified prologue pack.
// ---------------------------------------------------------------------------
__global__ __launch_bounds__(256)
void k_pack(const unsigned* __restrict__ adjw,
            unsigned long long* __restrict__ bitmap) {
    int id = blockIdx.x * 256 + threadIdx.x;      // [0, 524288)
    int grow = id >> 5, pc = id & 31;
    const unsigned* src = adjw + (size_t)grow * N_ + pc * 64;
    unsigned long long bits = 0;
#pragma unroll
    for (int w8 = 0; w8 < 16; ++w8) {
        uint4 a = *(const uint4*)(src + w8 * 4);
        bits |= (unsigned long long)((a.x & 1u) | ((a.y & 1u) << 1) |
                                     ((a.z & 1u) << 2) | ((a.w & 1u) << 3))
                << (w8 * 4);
    }
    bitmap[id] = bits;
}

// stage one 32 KB chunk tile: pure contiguous DMA (swizzle pre-baked).
// 4 waves x 8 instrs x (64 lanes x 16 B contiguous). Verified rounds 8/11.
__device__ __forceinline__ void stageB(const bf16* tile, char* dst,
                                       int w, int lane) {
#pragma unroll
    for (int r = 0; r < 8; ++r) {
        int off = (w * 8 + r) * 1024;               // bytes, wave-uniform
        const bf16* g = tile + off / 2 + lane * 8;
        __builtin_amdgcn_global_load_lds(
            (const __attribute__((address_space(1))) unsigned*)g,
            (__attribute__((address_space(3))) unsigned*)(dst + off),
            16, 0, 0);
    }
}

// ---------------------------------------------------------------------------
// Kernel C: fused masked-softmax attention + PV + ELU. R=32 rows/block,
// 512 blocks x 256 thr; waves = (mt, jh) -- R8's VALU-optimal mapping, one
// af per wave per chunk. Masks from the global bitmap (8 KB/block prologue
// read); B chunks DMA'd to dbuf LDS; 16 ds_read_b128 + 17 MFMA per wave per
// chunk; l via ones-MFMA; clamp keeps arithmetic NaN/Inf-proof. No HBM
// traffic in or near the main loop.
// ---------------------------------------------------------------------------
__global__ __launch_bounds__(256)
void k_attn(const unsigned long long* __restrict__ bitmap,
            const bf16* __restrict__ WhT2, const float* __restrict__ s2ws,
            const float* __restrict__ t2ws, const void* __restrict__ hv,
            void* __restrict__ outv) {
    int isb = detect_bf16(hv);
    int bid = blockIdx.x;
    int b = bid >> 6, itile = bid & 63, i0 = itile * 32;
    int tid = threadIdx.x;
    int w = tid >> 6, lane = tid & 63, m = lane & 15, q = lane >> 4;
    int mt = w >> 1, jh = w & 1;

    __shared__ __align__(16) char smem[78080];
    char* Bbuf0 = smem;                                       // 32 KB
    char* Bbuf1 = smem + 32768;                               // 32 KB
    unsigned long long* pack64 = (unsigned long long*)(smem + 65536); // [32][33]
    f16*   tLDS = (f16*)(smem + 65536 + 8448);                // [2048]
    float* red  = (float*)smem;              // epilogue overlay [32][260]
    __shared__ float lLDS[32];

    // ---- prologue (all small reads) ----
#pragma unroll
    for (int k = 0; k < 8; ++k) {
        int idx = k * 256 + tid;
        tLDS[idx] = (f16)t2ws[b * N_ + idx];
    }
    float s2i = s2ws[b * N_ + i0 + mt * 16 + m];
    {
        const unsigned long long* bm = bitmap + ((size_t)(b * N_ + i0)) * 32;
#pragma unroll
        for (int k = 0; k < 4; ++k) {
            int id = tid * 4 + k;                 // [0,1024) = prow*32 + pc
            pack64[(id >> 5) * 33 + (id & 31)] = bm[id];
        }
    }
    const size_t tilestep = (size_t)F_ * 64;      // 16384 elems per chunk tile
    const bf16* btiles = WhT2 + (size_t)(b * 32) * tilestep;
    stageB(btiles, Bbuf0, w, lane);
    __syncthreads();

    bf16x8 ones;
#pragma unroll
    for (int k = 0; k < 8; ++k) ones[k] = (bf16)1.0f;

    f32x4 acc[16];
#pragma unroll
    for (int ft = 0; ft < 16; ++ft) acc[ft] = (f32x4){0.f, 0.f, 0.f, 0.f};
    f32x4 acc_l = {0.f, 0.f, 0.f, 0.f};

    int psl = (jh * 4 + q) ^ (m & 7);             // phys 16B slot (baked swizzle)
    int byi = jh * 4 + q;                         // byte index into u64

    for (int c = 0; c < 32; ++c) {
        char* Bcur = (c & 1) ? Bbuf1 : Bbuf0;
        if (c < 31)
            stageB(btiles + (size_t)(c + 1) * tilestep,
                   (c & 1) ? Bbuf0 : Bbuf1, w, lane);

        unsigned long long pb = pack64[(mt * 16 + m) * 33 + c];
        unsigned bits8 = (unsigned)(pb >> (byi * 8)) & 0xFFu;
        f16x8 tv = *(const f16x8*)(tLDS + c * 64 + jh * 32 + q * 8);

        bf16x8 af;
#pragma unroll
        for (int qq = 0; qq < 8; ++qq) {
            float x = s2i + (float)tv[qq];
            x = fmaxf(x, 0.2f * x);                   // LeakyReLU (log2-scaled)
            x = fminf(fmaxf(x, -120.f), 60.f);        // NaN/Inf-proof clamp
            float pv = ((bits8 >> qq) & 1u) ? __builtin_amdgcn_exp2f(x) : 0.f;
            af[qq] = (bf16)pv;
        }
        acc_l = __builtin_amdgcn_mfma_f32_16x16x32_bf16(af, ones, acc_l, 0, 0, 0);
#pragma unroll
        for (int ft = 0; ft < 16; ++ft) {
            int fr = ft * 16 + m;
            bf16x8 bfr = *(const bf16x8*)(Bcur + fr * 128 + psl * 16);
            acc[ft] = __builtin_amdgcn_mfma_f32_16x16x32_bf16(af, bfr, acc[ft], 0, 0, 0);
        }
        __syncthreads();
    }

    // ---- epilogue: cross-jh reduce (Bbufs dead; loop's last barrier passed) ----
    if (jh == 1) {
#pragma unroll
        for (int r = 0; r < 4; ++r) {
            int row = mt * 16 + q * 4 + r;
#pragma unroll
            for (int ft = 0; ft < 16; ++ft)
                red[row * 260 + ft * 16 + m] = acc[ft][r];
            if (m == 0) { red[row * 260 + 256] = acc_l[r]; lLDS[row] = acc_l[r]; }
        }
    }
    __syncthreads();
    if (jh == 0) {
#pragma unroll
        for (int r = 0; r < 4; ++r) {
            int row = mt * 16 + q * 4 + r;
            float lf = acc_l[r] + lLDS[row];
            float rl = (lf > 0.f) ? (1.f / lf) : 0.f;
            size_t ob = ((size_t)b * N_ + i0 + row) * F_;
#pragma unroll
            for (int ft = 0; ft < 16; ++ft) {
                int f = ft * 16 + m;
                float v = acc[ft][r] + red[row * 260 + f];
                v *= rl;
                v = (v > 0.f) ? v : (__builtin_amdgcn_exp2f(v * LOG2E) - 1.f);
                if (isb) ((bf16*)outv)[ob + f] = (bf16)v;
                else     ((float*)outv)[ob + f] = v;
            }
        }
    }
}

// ---------------------------------------------------------------------------
extern "C" void kernel_launch(void* const* d_in, const int* in_sizes, int n_in,
                              void* d_out, int out_size, void* d_ws, size_t ws_size,
                              hipStream_t stream) {
    (void)in_sizes; (void)n_in; (void)out_size; (void)ws_size;
    const void* h    = d_in[0];
    const unsigned* adjw = (const unsigned*)d_in[1];  // read-only now
    const void* W_w  = d_in[2];
    const void* W_b  = d_in[3];
    const void* ai_w = d_in[4];
    const void* ai_b = d_in[5];
    const void* aj_w = d_in[6];
    const void* aj_b = d_in[7];

    // ws layout (evidence: harness fills 537 MB -> ws_size ~512 MB):
    //   [0, 8 MiB)            WhT2
    //   [8 MiB, +64 KiB)      s2 (f32[16384])
    //   [.., +64 KiB)         t2 (f32[16384])
    //   [8 MiB+128 KiB, +4 MiB) mask bitmap (u64[524288])
    char* wsb = (char*)d_ws;
    bf16*  WhT2 = (bf16*)wsb;
    float* s2ws = (float*)(wsb + (8u << 20));
    float* t2ws = (float*)(wsb + (8u << 20) + (64u << 10));
    unsigned long long* bitmap =
        (unsigned long long*)(wsb + (8u << 20) + (128u << 10));

    k_wht <<<dim3(1024), dim3(256), 0, stream>>>(h, W_w, W_b, ai_w, ai_b,
                                                 aj_w, aj_b, WhT2, s2ws, t2ws);
    k_pack<<<dim3(2048), dim3(256), 0, stream>>>(adjw, bitmap);
    k_attn<<<dim3(512),  dim3(256), 0, stream>>>(bitmap, WhT2, s2ws, t2ws,
                                                 h, d_out);
}